// Round 6
// baseline (1041.482 us; speedup 1.0000x reference)
//
#include <hip/hip_runtime.h>

typedef unsigned short u16;
using bf16x8 = __attribute__((ext_vector_type(8))) __bf16;
using f32x4  = __attribute__((ext_vector_type(4))) float;

// ---------------- helpers ----------------
__device__ __forceinline__ u16 f2bf(float f) {
  unsigned u = __builtin_bit_cast(unsigned, f);
  u += 0x7FFFu + ((u >> 16) & 1u);       // round-to-nearest-even
  return (u16)(u >> 16);
}
__device__ __forceinline__ float bf2f(u16 s) {
  unsigned u = ((unsigned)s) << 16;
  return __builtin_bit_cast(float, u);
}
__device__ __forceinline__ void lds16(const void* g, void* l) {
  __builtin_amdgcn_global_load_lds(
      (const __attribute__((address_space(1))) void*)g,
      (__attribute__((address_space(3))) void*)l, 16, 0, 0);
}

#define MM(A, B, C) __builtin_amdgcn_mfma_f32_16x16x32_bf16(A, B, C, 0, 0, 0)

#define PH_TOP() \
  __builtin_amdgcn_s_barrier(); \
  asm volatile("s_waitcnt lgkmcnt(0)" ::: "memory"); \
  __builtin_amdgcn_sched_barrier(0);

#define MFMA8(MA, MB) \
  __builtin_amdgcn_s_setprio(1); \
  acc[MA][0] = MM(a0, b0, acc[MA][0]); \
  acc[MA][1] = MM(a0, b1, acc[MA][1]); \
  acc[MA][2] = MM(a0, b2, acc[MA][2]); \
  acc[MA][3] = MM(a0, b3, acc[MA][3]); \
  acc[MB][0] = MM(a1, b0, acc[MB][0]); \
  acc[MB][1] = MM(a1, b1, acc[MB][1]); \
  acc[MB][2] = MM(a1, b2, acc[MB][2]); \
  acc[MB][3] = MM(a1, b3, acc[MB][3]); \
  __builtin_amdgcn_s_setprio(0);

// ===========================================================================
// 256x256 4-phase double-buffered GEMM core, 2 blocks/CU variant.
// BM=BN=256, BK=32, 512 thr = 8 waves (2M x 4N), per-wave 128x64, acc[8][4]
// (round-2 proven fragment/epilogue mapping). LDS = 2buf x (A 16K + B 16K)
// = 64 KiB -> with launch_bounds(512,4) TWO blocks co-resident per CU
// (the round-2 schedule at 1 block/CU wasted the 312-tile tail; m114-style
// cross-block overlap fills each block's drain stalls).
//
// Per K-tile T (buf = T&1): 4 phases, phase q reads A m-frags {2q,2q+1}
// (+ all 4 B n-frags at q==0), 8 MFMA each; one stage-op of tile T+1 into
// buf^1 per phase (A-half0, A-half1, B-half0, B-half1); vmcnt(0) drain only
// at phase-3 end, >=3 phases after issue. WAR on buf^1: its tile-(T-1)
// readers did lgkm0 before the T-1 end barrier, which precedes any phase-0
// stage issue. RAW: per-tile vmcnt(0) + barrier.
//
// Swizzle (64B rows, 4 x 16B chunks): LDS[r][c] holds global chunk
// c ^ ((r>>1)&3); read side same XOR -> 2-way max = free (0 measured,
// rounds 3-5).  C/D: col = lane&15, row = (lane>>4)*4 + reg  [m89].
// ===========================================================================
__device__ __forceinline__ void gemm2(
    const u16* aS0, const u16* aS1, const u16* bS0, const u16* bS1,
    int NT, int t, u16* As, u16* Bs, f32x4 (&acc)[8][4])
{
  const int lane = t & 63, fr = lane & 15, q4 = lane >> 4;
  const int w = t >> 6, wm = w >> 2, wn = w & 3;
  const int sxy = (q4 ^ ((fr >> 1) & 3)) * 8;     // read-side chunk swizzle
  const int aoff = (wm * 128 + fr) * 32 + sxy;    // + mt*512
  const int boff = (wn * 64 + fr) * 32 + sxy;     // + nt*512

  // prologue: stage tile 0 into buf 0
  lds16(aS0, As + t * 8);
  lds16(aS1, As + 4096 + t * 8);
  lds16(bS0, Bs + t * 8);
  lds16(bS1, Bs + 4096 + t * 8);
  asm volatile("s_waitcnt vmcnt(0)" ::: "memory");
  __builtin_amdgcn_s_barrier();

  for (int T = 0; T < NT; ++T) {
    const int pb = T & 1;
    const u16* Ab = As + pb * 8192;
    const u16* Bb = Bs + pb * 8192;
    u16* An = As + (pb ^ 1) * 8192;
    u16* Bn = Bs + (pb ^ 1) * 8192;
    const bool s1 = (T + 1 < NT);
    const size_t k1 = (size_t)(T + 1) * 32;
    bf16x8 a0, a1, b0, b1, b2, b3;

    // phase 0: A frags 0,1 + all B frags; stage A-half0[T+1]
    a0 = *(const bf16x8*)(Ab + aoff);
    a1 = *(const bf16x8*)(Ab + aoff + 512);
    b0 = *(const bf16x8*)(Bb + boff);
    b1 = *(const bf16x8*)(Bb + boff + 512);
    b2 = *(const bf16x8*)(Bb + boff + 1024);
    b3 = *(const bf16x8*)(Bb + boff + 1536);
    if (s1) lds16(aS0 + k1, An + t * 8);
    PH_TOP();
    MFMA8(0, 1);
    __builtin_amdgcn_s_barrier();

    // phase 1: A frags 2,3; stage A-half1[T+1]
    a0 = *(const bf16x8*)(Ab + aoff + 1024);
    a1 = *(const bf16x8*)(Ab + aoff + 1536);
    if (s1) lds16(aS1 + k1, An + 4096 + t * 8);
    PH_TOP();
    MFMA8(2, 3);
    __builtin_amdgcn_s_barrier();

    // phase 2: A frags 4,5; stage B-half0[T+1]
    a0 = *(const bf16x8*)(Ab + aoff + 2048);
    a1 = *(const bf16x8*)(Ab + aoff + 2560);
    if (s1) lds16(bS0 + k1, Bn + t * 8);
    PH_TOP();
    MFMA8(4, 5);
    __builtin_amdgcn_s_barrier();

    // phase 3: A frags 6,7; stage B-half1[T+1]; drain
    a0 = *(const bf16x8*)(Ab + aoff + 3072);
    a1 = *(const bf16x8*)(Ab + aoff + 3584);
    if (s1) lds16(bS1 + k1, Bn + 4096 + t * 8);
    PH_TOP();
    MFMA8(6, 7);
    if (s1) asm volatile("s_waitcnt vmcnt(0)" ::: "memory");
    __builtin_amdgcn_s_barrier();
  }
}

// ===========================================================================
// Ring-3 wide-wave GEMM core (round-4, kept for g_oproj2). BM=256, BN=128,
// BK=32, 256 thr = 4 waves (2M x 2N), per-wave 128x64, acc[8][4]. 72 KiB.
// ===========================================================================
#define STG6(TT, QQ) \
  lds16(aS0 + (size_t)(TT) * 32, As + (QQ) * 8192 + t * 8); \
  lds16(aS1 + (size_t)(TT) * 32, As + (QQ) * 8192 + 2048 + t * 8); \
  lds16(aS2 + (size_t)(TT) * 32, As + (QQ) * 8192 + 4096 + t * 8); \
  lds16(aS3 + (size_t)(TT) * 32, As + (QQ) * 8192 + 6144 + t * 8); \
  lds16(bS0 + (size_t)(TT) * 32, Bs + (QQ) * 4096 + t * 8); \
  lds16(bS1 + (size_t)(TT) * 32, Bs + (QQ) * 4096 + 2048 + t * 8);

__device__ __forceinline__ void gemm_w4(
    const u16* aS0, const u16* aS1, const u16* aS2, const u16* aS3,
    const u16* bS0, const u16* bS1,
    int NT, int t, u16* As, u16* Bs, f32x4 (&acc)[8][4])
{
  const int lane = t & 63, fr = lane & 15, q4 = lane >> 4;
  const int w = t >> 6, wm = w >> 1, wn = w & 1;
  const int sxy = (q4 ^ ((fr >> 1) & 3)) * 8;
  const int aoff = (wm * 128 + fr) * 32 + sxy;
  const int boff = (wn * 64 + fr) * 32 + sxy;

  STG6(0, 0);
  STG6(1, 1);
  asm volatile("s_waitcnt vmcnt(6)" ::: "memory");
  __builtin_amdgcn_s_barrier();

  for (int T = 0; T < NT; ++T) {
    const int q = T % 3;
    const u16* Ab = As + q * 8192;
    const u16* Bb = Bs + q * 4096;
    bf16x8 af[8], bfv[4];
#pragma unroll
    for (int mt = 0; mt < 8; ++mt)
      af[mt] = *(const bf16x8*)(Ab + aoff + mt * 512);
#pragma unroll
    for (int nt = 0; nt < 4; ++nt)
      bfv[nt] = *(const bf16x8*)(Bb + boff + nt * 512);
    const bool s2 = (T + 2 < NT);
    if (s2) { const int q2 = (T + 2) % 3; STG6(T + 2, q2); }
    asm volatile("s_waitcnt lgkmcnt(0)" ::: "memory");
    __builtin_amdgcn_sched_barrier(0);
    __builtin_amdgcn_s_setprio(1);
#pragma unroll
    for (int mt = 0; mt < 8; ++mt)
#pragma unroll
      for (int nt = 0; nt < 4; ++nt)
        acc[mt][nt] = MM(af[mt], bfv[nt], acc[mt][nt]);
    __builtin_amdgcn_s_setprio(0);
    if (s2) asm volatile("s_waitcnt vmcnt(6)" ::: "memory");
    else    asm volatile("s_waitcnt vmcnt(0)" ::: "memory");
    __builtin_amdgcn_s_barrier();
  }
}

// ---------------------------------------------------------------------------
// Fused prep: z<8 -> weight transpose jobs, z=8/9 -> activation f32->bf16 cvt
// ---------------------------------------------------------------------------
struct PrepArgs {
  const float* tsrc[8]; u16* tdst[8]; int tK[8]; int tN[8];
  const float* csrc[2]; u16* cdst[2]; int cn4[2];
};

__global__ __launch_bounds__(256) void g_prep(PrepArgs a)
{
  __shared__ float T[32][33];
  const int z = blockIdx.z;
  if (z < 8) {
    const int Krows = a.tK[z], Ncols = a.tN[z];
    const int k0 = blockIdx.y * 32, n0 = blockIdx.x * 32;
    if (k0 >= Krows || n0 >= Ncols) return;
    const float* W = a.tsrc[z];
    u16* Wt = a.tdst[z];
    const int tx = threadIdx.x & 31, ty = threadIdx.x >> 5;
#pragma unroll
    for (int r = 0; r < 4; ++r)
      T[ty + r * 8][tx] = W[(size_t)(k0 + ty + r * 8) * Ncols + n0 + tx];
    __syncthreads();
#pragma unroll
    for (int r = 0; r < 4; ++r)
      Wt[(size_t)(n0 + ty + r * 8) * Krows + k0 + tx] = f2bf(T[tx][ty + r * 8]);
  } else {
    const int j = z - 8;
    const int n4 = a.cn4[j];
    const float* X = a.csrc[j];
    u16* Y = a.cdst[j];
    const int blk = blockIdx.y * gridDim.x + blockIdx.x;
    const int stride = gridDim.x * gridDim.y * 256;
    for (int i = blk * 256 + threadIdx.x; i < n4; i += stride) {
      float4 f = ((const float4*)X)[i];
      ushort4 u;
      u.x = f2bf(f.x); u.y = f2bf(f.y); u.z = f2bf(f.z); u.w = f2bf(f.w);
      ((ushort4*)Y)[i] = u;
    }
  }
}

// ---------------------------------------------------------------------------
// Fused QKV projection, 256x256 4-phase dbuf core, 2 blocks/CU.
// Grid (24, 13): y<12 vlm (m0=y*256, K=2048), y==12 exp (m0=0, K=1024).
// ---------------------------------------------------------------------------
__global__ __launch_bounds__(512, 4) void g_proj_qkv(
    const u16* __restrict__ Xv, const u16* __restrict__ Xe,
    const u16* __restrict__ Wv_cat, const u16* __restrict__ We_cat,
    u16* __restrict__ Qb, u16* __restrict__ Kb, u16* __restrict__ Vt)
{
  __shared__ __align__(16) u16 As[16384], Bs[16384];   // 64 KiB
  const int y = blockIdx.y;
  const u16* X; const u16* Wt; int Kdim, rows_pb, l_off, m0;
  if (y < 12) { X = Xv; Wt = Wv_cat; Kdim = 2048; rows_pb = 768; l_off = 0; m0 = y * 256; }
  else        { X = Xe; Wt = We_cat; Kdim = 1024; rows_pb = 64;  l_off = 768; m0 = 0; }
  const int t = threadIdx.x;
  const int n0 = blockIdx.x * 256;
  const int r0 = t >> 2;
  const int swk = ((t & 3) ^ ((r0 >> 1) & 3)) * 8;  // stage-source swizzle
  const u16* aS0 = X + (size_t)(m0 + r0) * Kdim + swk;
  const u16* aS1 = X + (size_t)(m0 + r0 + 128) * Kdim + swk;
  const u16* bS0 = Wt + (size_t)(n0 + r0) * Kdim + swk;
  const u16* bS1 = Wt + (size_t)(n0 + r0 + 128) * Kdim + swk;

  f32x4 acc[8][4] = {};
  gemm2(aS0, aS1, bS0, bS1, Kdim >> 5, t, As, Bs, acc);

  const int lane = t & 63, q4 = lane >> 4;
  const int wn = (t >> 6) & 3, wm = t >> 8;
  const int rbase = m0 + wm * 128 + q4 * 4;
  const int cbase = n0 + wn * 64 + (lane & 15);
  const int sect = n0 >> 11;               // block-uniform: 0=Q 1=K 2=V

  if (sect < 2) {
    u16* Out = (sect == 0) ? Qb : Kb;
#pragma unroll
    for (int mt = 0; mt < 8; ++mt) {
#pragma unroll
      for (int r = 0; r < 4; ++r) {
        int m = rbase + mt * 16 + r;
        int b = m / rows_pb;
        int l = m - b * rows_pb + l_off;
#pragma unroll
        for (int nt = 0; nt < 4; ++nt) {
          int nloc = (cbase + nt * 16) & 2047;
          Out[(((size_t)(b * 8 + (nloc >> 8))) * 832 + l) * 256 + (nloc & 255)] =
              f2bf(acc[mt][nt][r]);
        }
      }
    }
  } else {
#pragma unroll
    for (int mt = 0; mt < 8; ++mt) {
      int mb = rbase + mt * 16;
      int b = mb / rows_pb;
      int l = mb - b * rows_pb + l_off;     // 4-aligned, no batch crossing
#pragma unroll
      for (int nt = 0; nt < 4; ++nt) {
        int nloc = (cbase + nt * 16) & 2047;
        ushort4 p;
        p.x = f2bf(acc[mt][nt][0]); p.y = f2bf(acc[mt][nt][1]);
        p.z = f2bf(acc[mt][nt][2]); p.w = f2bf(acc[mt][nt][3]);
        *(ushort4*)&Vt[(((size_t)(b * 8 + (nloc >> 8))) * 256 + (nloc & 255)) * 832 + l] = p;
      }
    }
  }
}

// ---------------------------------------------------------------------------
// RoPE in place on bf16 Q,K (bh, 832, 256). Q additionally scaled by 1/16.
// ---------------------------------------------------------------------------
__global__ __launch_bounds__(128) void g_rope(
    u16* __restrict__ Q, u16* __restrict__ Kx, const int* __restrict__ pos)
{
  const int blk = blockIdx.x;
  const int l = blk % 832, bh = blk / 832, b = bh >> 3;
  const int i = threadIdx.x;
  const float p = (float)pos[b * 832 + l];
  const float inv = exp2f(-(float)i * 0.103810252965229910f);  // log2(1e4)/128
  const float ang = p * inv;
  const float c = cosf(ang), s = sinf(ang);
  const size_t base = ((size_t)bh * 832 + l) * 256;

  float x1 = bf2f(Q[base + i]), x2 = bf2f(Q[base + i + 128]);
  Q[base + i]       = f2bf((x1 * c - x2 * s) * 0.0625f);
  Q[base + i + 128] = f2bf((x2 * c + x1 * s) * 0.0625f);
  x1 = bf2f(Kx[base + i]); x2 = bf2f(Kx[base + i + 128]);
  Kx[base + i]       = f2bf(x1 * c - x2 * s);
  Kx[base + i + 128] = f2bf(x2 * c + x1 * s);
}

// ---------------------------------------------------------------------------
// Single-pass flash attention v2 (round-5 proven). Grid 416, block 256.
// Static-max softmax + double-buffered K/V with issue-early/wait-late.
// ---------------------------------------------------------------------------
__global__ __launch_bounds__(256) void g_flash(
    const u16* __restrict__ Qb, const u16* __restrict__ Kb,
    const u16* __restrict__ Vt, const float* __restrict__ mask,
    u16* __restrict__ AO)
{
  __shared__ __align__(16) u16 Ks[2][8192];
  __shared__ __align__(16) u16 Vs[2][8192];
  __shared__ __align__(16) u16 Ps[2048];
  const int t = threadIdx.x;
  const int lane = t & 63, w = t >> 6, quad = lane >> 4;
  const int wb = w * 512;

  const int id = blockIdx.x;
  const int x = id & 7, k = id >> 3;
  const int bh = x + 8 * (k / 13);
  const int q0 = (k % 13) * 64;
  const int b = bh >> 3, h = bh & 7;

  const u16* Ksrc = Kb + (size_t)bh * 832 * 256;
  const u16* Vsrc = Vt + (size_t)bh * 256 * 832;
  const float* Mrow = mask + (size_t)b * 832 * 832;

#define STGK(KT, BUF) \
  _Pragma("unroll") \
  for (int p = 0; p < 4; ++p) { \
    int c = p * 256 + t; \
    int row = c >> 5, chk = c & 31; \
    lds16(Ksrc + (size_t)((KT) * 32 + row) * 256 + ((chk ^ (row & 7)) * 8), \
          Ks[BUF] + c * 8); \
  }
#define STGV(KT, BUF) \
  _Pragma("unroll") \
  for (int p = 0; p < 4; ++p) { \
    int c = p * 256 + t; \
    int row = c >> 3; \
    int lc = (c & 7) ^ (row & 7); \
    int dh = 2 * row + (lc >> 2); \
    lds16(Vsrc + (size_t)dh * 832 + (KT) * 32 + (lc & 3) * 8, Vs[BUF] + c * 8); \
  }

  bf16x8 qf[8];
#pragma unroll
  for (int kf = 0; kf < 8; ++kf)
    qf[kf] = *(const bf16x8*)(
        Qb + ((size_t)bh * 832 + q0 + w * 16 + (lane & 15)) * 256 +
        kf * 32 + quad * 8);

  float lsum[4] = {0.f, 0.f, 0.f, 0.f};
  f32x4 oa[16] = {};

  STGK(0, 0); STGV(0, 0);
  asm volatile("s_waitcnt vmcnt(0)" ::: "memory");
  __builtin_amdgcn_s_barrier();

  for (int kt = 0; kt < 26; ++kt) {
    const int buf = kt & 1;
    if (kt + 1 < 26) { STGK(kt + 1, buf ^ 1); STGV(kt + 1, buf ^ 1); }

    float mv[4][2];
#pragma unroll
    for (int r = 0; r < 4; ++r) {
      int q = q0 + w * 16 + quad * 4 + r;
      const float* mrp = Mrow + (size_t)q * 832 + kt * 32 + (lane & 15);
      mv[r][0] = mrp[0];
      mv[r][1] = mrp[16];
    }

    f32x4 sa[2] = {};
#pragma unroll
    for (int ks = 0; ks < 8; ++ks)
#pragma unroll
      for (int nt = 0; nt < 2; ++nt) {
        int krow = nt * 16 + (lane & 15);
        bf16x8 kb = *(const bf16x8*)(
            Ks[buf] + krow * 256 + (((ks * 4 + quad) ^ (krow & 7)) * 8));
        sa[nt] = MM(qf[ks], kb, sa[nt]);
      }

#pragma unroll
    for (int r = 0; r < 4; ++r) {
      int prow = quad * 4 + r;
      float p0 = __expf(sa[0][r] + mv[r][0]);
      float p1 = __expf(sa[1][r] + mv[r][1]);
      lsum[r] += p0 + p1;
      int s0 = ((lane >> 3) & 1) ^ quad;
      int s1 = (2 | ((lane >> 3) & 1)) ^ quad;
      Ps[wb + prow * 32 + s0 * 8 + (lane & 7)] = f2bf(p0);
      Ps[wb + prow * 32 + s1 * 8 + (lane & 7)] = f2bf(p1);
    }

    int prow2 = lane & 15;
    bf16x8 pa = *(const bf16x8*)(
        Ps + wb + prow2 * 32 + ((quad ^ ((prow2 >> 2) & 3)) * 8));
#pragma unroll
    for (int nt = 0; nt < 16; ++nt) {
      int dh = nt * 16 + (lane & 15);
      int row = dh >> 1;
      int lc = ((dh & 1) << 2) | quad;
      bf16x8 vb = *(const bf16x8*)(Vs[buf] + row * 64 + ((lc ^ (row & 7)) * 8));
      oa[nt] = MM(pa, vb, oa[nt]);
    }

    asm volatile("s_waitcnt vmcnt(0)" ::: "memory");  // kt+1 stage landed
    __builtin_amdgcn_s_barrier();
  }

  float linv[4];
#pragma unroll
  for (int r = 0; r < 4; ++r) {
    float s = lsum[r];
    s += __shfl_xor(s, 1);
    s += __shfl_xor(s, 2);
    s += __shfl_xor(s, 4);
    s += __shfl_xor(s, 8);
    linv[r] = 1.0f / s;
  }
#pragma unroll
  for (int r = 0; r < 4; ++r) {
    size_t l = q0 + w * 16 + quad * 4 + r;
    u16* dst = AO + ((size_t)b * 832 + l) * 2048 + h * 256 + (lane & 15);
#pragma unroll
    for (int nt = 0; nt < 16; ++nt)
      dst[nt * 16] = f2bf(oa[nt][r] * linv[r]);
  }
#undef STGK
#undef STGV
}

// ---------------------------------------------------------------------------
// Fused output projection, wide-wave ring-3 core. Grid (16, 13):
// y<12 vlm (N=2048), y==12 exp (x<8, N=1024). K=2048 both. Block 256 thr.
// ---------------------------------------------------------------------------
__global__ __launch_bounds__(256, 2) void g_oproj2(
    const u16* __restrict__ AO, const u16* __restrict__ Wov,
    const u16* __restrict__ Woe, float* __restrict__ out)
{
  __shared__ __align__(16) u16 As[24576], Bs[12288];   // 72 KiB
  const int y = blockIdx.y;
  const u16* Wt; float* C; int N, rows_pb, l_off, m0;
  if (y < 12) { Wt = Wov; C = out; N = 2048; rows_pb = 768; l_off = 0; m0 = y * 256; }
  else {
    if (blockIdx.x >= 8) return;
    Wt = Woe; C = out + (size_t)4 * 768 * 2048; N = 1024; rows_pb = 64; l_off = 768; m0 = 0;
  }
  const int t = threadIdx.x;
  const int n0 = blockIdx.x * 128;
  const int r0 = t >> 2;
  const int swk = ((t & 3) ^ ((t >> 3) & 3)) * 8;
  const u16* aSp[4];
#pragma unroll
  for (int i = 0; i < 4; ++i) {
    int mr = m0 + i * 64 + r0;
    int ba = mr / rows_pb;
    aSp[i] = AO + ((size_t)ba * 832 + (mr - ba * rows_pb) + l_off) * 2048 + swk;
  }
  const u16* bS0 = Wt + (size_t)(n0 + r0) * 2048 + swk;
  const u16* bS1 = Wt + (size_t)(n0 + r0 + 64) * 2048 + swk;

  f32x4 acc[8][4] = {};
  gemm_w4(aSp[0], aSp[1], aSp[2], aSp[3], bS0, bS1, 64, t, As, Bs, acc);

  const int lane = t & 63, fr = lane & 15, q4 = lane >> 4;
  const int w = t >> 6, wm = w >> 1, wn = w & 1;
  const int rbase = m0 + wm * 128 + q4 * 4;
  const int cbase = n0 + wn * 64 + fr;
#pragma unroll
  for (int mt = 0; mt < 8; ++mt)
#pragma unroll
    for (int rr = 0; rr < 4; ++rr) {
      size_t m = rbase + mt * 16 + rr;
#pragma unroll
      for (int nt = 0; nt < 4; ++nt)
        C[m * N + cbase + nt * 16] = acc[mt][nt][rr];
    }
}

// ---------------------------------------------------------------------------
extern "C" void kernel_launch(void* const* d_in, const int* in_sizes, int n_in,
                              void* d_out, int out_size, void* d_ws, size_t ws_size,
                              hipStream_t stream)
{
  const float* vlm_h = (const float*)d_in[0];
  const float* exp_h = (const float*)d_in[1];
  const float* mask  = (const float*)d_in[2];
  const int*   pos   = (const int*)d_in[3];
  const float* wq_v  = (const float*)d_in[4];
  const float* wk_v  = (const float*)d_in[5];
  const float* wv_v  = (const float*)d_in[6];
  const float* wo_v  = (const float*)d_in[7];
  const float* wq_e  = (const float*)d_in[8];
  const float* wk_e  = (const float*)d_in[9];
  const float* wv_e  = (const float*)d_in[10];
  const float* wo_e  = (const float*)d_in[11];
  float* out = (float*)d_out;

  // ---- workspace layout (~118 MB) ----
  u16* U = (u16*)d_ws;
  u16* Xv   = U; U += (size_t)4 * 768 * 2048;
  u16* Xe   = U; U += (size_t)4 * 64 * 1024;
  u16* Wcv  = U; U += (size_t)6144 * 2048;   // [Wq_v^T | Wk_v^T | Wv_v^T]
  u16* Wce  = U; U += (size_t)6144 * 1024;   // [Wq_e^T | Wk_e^T | Wv_e^T]
  u16* Wov  = U; U += (size_t)2048 * 2048;
  u16* Woe  = U; U += (size_t)1024 * 2048;
  u16* Qb   = U; U += (size_t)32 * 832 * 256;
  u16* Kb   = U; U += (size_t)32 * 832 * 256;
  u16* Vt   = U; U += (size_t)32 * 256 * 832;
  u16* AO   = U; U += (size_t)4 * 832 * 2048;

  const dim3 blk(256);

  PrepArgs pa;
  pa.tsrc[0] = wq_v; pa.tdst[0] = Wcv;                        pa.tK[0] = 2048; pa.tN[0] = 2048;
  pa.tsrc[1] = wk_v; pa.tdst[1] = Wcv + (size_t)2048 * 2048;  pa.tK[1] = 2048; pa.tN[1] = 2048;
  pa.tsrc[2] = wv_v; pa.tdst[2] = Wcv + (size_t)4096 * 2048;  pa.tK[2] = 2048; pa.tN[2] = 2048;
  pa.tsrc[3] = wo_v; pa.tdst[3] = Wov;                        pa.tK[3] = 2048; pa.tN[3] = 2048;
  pa.tsrc[4] = wq_e; pa.tdst[4] = Wce;                        pa.tK[4] = 1024; pa.tN[4] = 2048;
  pa.tsrc[5] = wk_e; pa.tdst[5] = Wce + (size_t)2048 * 1024;  pa.tK[5] = 1024; pa.tN[5] = 2048;
  pa.tsrc[6] = wv_e; pa.tdst[6] = Wce + (size_t)4096 * 1024;  pa.tK[6] = 1024; pa.tN[6] = 2048;
  pa.tsrc[7] = wo_e; pa.tdst[7] = Woe;                        pa.tK[7] = 2048; pa.tN[7] = 1024;
  pa.csrc[0] = vlm_h; pa.cdst[0] = Xv; pa.cn4[0] = 1572864;
  pa.csrc[1] = exp_h; pa.cdst[1] = Xe; pa.cn4[1] = 65536;
  g_prep<<<dim3(64, 64, 10), blk, 0, stream>>>(pa);

  // fused QKV projection, 256x256 4-phase dbuf core, 2 blocks/CU
  g_proj_qkv<<<dim3(24, 13, 1), dim3(512), 0, stream>>>(Xv, Xe, Wcv, Wce, Qb, Kb, Vt);

  g_rope<<<dim3(32 * 832), dim3(128), 0, stream>>>(Qb, Kb, pos);

  // flash attention v2 (static-max softmax + double-buffered K/V)
  g_flash<<<dim3(416), blk, 0, stream>>>(Qb, Kb, Vt, mask, AO);

  g_oproj2<<<dim3(16, 13, 1), blk, 0, stream>>>(AO, Wov, Woe, out);
}

// Round 7
// 396.139 us; speedup vs baseline: 2.6291x; 2.6291x over previous
//
#include <hip/hip_runtime.h>

typedef unsigned short u16;
using bf16x8 = __attribute__((ext_vector_type(8))) __bf16;
using u16x8  = __attribute__((ext_vector_type(8))) unsigned short;
using f32x4  = __attribute__((ext_vector_type(4))) float;

// ---------------- helpers ----------------
__device__ __forceinline__ u16 f2bf(float f) {
  unsigned u = __builtin_bit_cast(unsigned, f);
  u += 0x7FFFu + ((u >> 16) & 1u);       // round-to-nearest-even
  return (u16)(u >> 16);
}
__device__ __forceinline__ float bf2f(u16 s) {
  unsigned u = ((unsigned)s) << 16;
  return __builtin_bit_cast(float, u);
}
__device__ __forceinline__ void lds16(const void* g, void* l) {
  __builtin_amdgcn_global_load_lds(
      (const __attribute__((address_space(1))) void*)g,
      (__attribute__((address_space(3))) void*)l, 16, 0, 0);
}

#define MM(A, B, C) __builtin_amdgcn_mfma_f32_16x16x32_bf16(A, B, C, 0, 0, 0)

// ===========================================================================
// Ring-3 wide-wave GEMM core (round-4/5 proven, 111.5us on proj).
// BM=256, BN=128, BK=32, 256 thr = 4 waves (2M x 2N), per-wave 128x64,
// acc[8][4] (~120 VGPR at launch_bounds(256,2) -> 256 VGPR cap OK).
// LDS 72 KiB -> 2 blocks/CU.  NOTE (round-6 lesson): per-wave 128x64 tiles
// (128 acc VGPRs) REQUIRE the 256-reg budget; any launch_bounds forcing
// 128-reg cap spills accumulators to scratch (1.5 GB writes, 7x slower).
// ===========================================================================
#define STG6(TT, QQ) \
  lds16(aS0 + (size_t)(TT) * 32, As + (QQ) * 8192 + t * 8); \
  lds16(aS1 + (size_t)(TT) * 32, As + (QQ) * 8192 + 2048 + t * 8); \
  lds16(aS2 + (size_t)(TT) * 32, As + (QQ) * 8192 + 4096 + t * 8); \
  lds16(aS3 + (size_t)(TT) * 32, As + (QQ) * 8192 + 6144 + t * 8); \
  lds16(bS0 + (size_t)(TT) * 32, Bs + (QQ) * 4096 + t * 8); \
  lds16(bS1 + (size_t)(TT) * 32, Bs + (QQ) * 4096 + 2048 + t * 8);

__device__ __forceinline__ void gemm_w4(
    const u16* aS0, const u16* aS1, const u16* aS2, const u16* aS3,
    const u16* bS0, const u16* bS1,
    int NT, int t, u16* As, u16* Bs, f32x4 (&acc)[8][4])
{
  const int lane = t & 63, fr = lane & 15, q4 = lane >> 4;
  const int w = t >> 6, wm = w >> 1, wn = w & 1;
  const int sxy = (q4 ^ ((fr >> 1) & 3)) * 8;     // read-side chunk swizzle
  const int aoff = (wm * 128 + fr) * 32 + sxy;    // + mt*512
  const int boff = (wn * 64 + fr) * 32 + sxy;     // + nt*512

  STG6(0, 0);
  STG6(1, 1);
  asm volatile("s_waitcnt vmcnt(6)" ::: "memory");   // tile 0 landed
  __builtin_amdgcn_s_barrier();

  for (int T = 0; T < NT; ++T) {
    const int q = T % 3;
    const u16* Ab = As + q * 8192;
    const u16* Bb = Bs + q * 4096;
    bf16x8 af[8], bfv[4];
#pragma unroll
    for (int mt = 0; mt < 8; ++mt)
      af[mt] = *(const bf16x8*)(Ab + aoff + mt * 512);
#pragma unroll
    for (int nt = 0; nt < 4; ++nt)
      bfv[nt] = *(const bf16x8*)(Bb + boff + nt * 512);
    const bool s2 = (T + 2 < NT);
    if (s2) { const int q2 = (T + 2) % 3; STG6(T + 2, q2); }
    asm volatile("s_waitcnt lgkmcnt(0)" ::: "memory");
    __builtin_amdgcn_sched_barrier(0);
    __builtin_amdgcn_s_setprio(1);
#pragma unroll
    for (int mt = 0; mt < 8; ++mt)
#pragma unroll
      for (int nt = 0; nt < 4; ++nt)
        acc[mt][nt] = MM(af[mt], bfv[nt], acc[mt][nt]);
    __builtin_amdgcn_s_setprio(0);
    if (s2) asm volatile("s_waitcnt vmcnt(6)" ::: "memory");
    else    asm volatile("s_waitcnt vmcnt(0)" ::: "memory");
    __builtin_amdgcn_s_barrier();
  }
}

// ---------------------------------------------------------------------------
// Fused prep: z<8 -> weight transpose jobs, z=8/9 -> activation f32->bf16 cvt
// ---------------------------------------------------------------------------
struct PrepArgs {
  const float* tsrc[8]; u16* tdst[8]; int tK[8]; int tN[8];
  const float* csrc[2]; u16* cdst[2]; int cn4[2];
};

__global__ __launch_bounds__(256) void g_prep(PrepArgs a)
{
  __shared__ float T[32][33];
  const int z = blockIdx.z;
  if (z < 8) {
    const int Krows = a.tK[z], Ncols = a.tN[z];
    const int k0 = blockIdx.y * 32, n0 = blockIdx.x * 32;
    if (k0 >= Krows || n0 >= Ncols) return;
    const float* W = a.tsrc[z];
    u16* Wt = a.tdst[z];
    const int tx = threadIdx.x & 31, ty = threadIdx.x >> 5;
#pragma unroll
    for (int r = 0; r < 4; ++r)
      T[ty + r * 8][tx] = W[(size_t)(k0 + ty + r * 8) * Ncols + n0 + tx];
    __syncthreads();
#pragma unroll
    for (int r = 0; r < 4; ++r)
      Wt[(size_t)(n0 + ty + r * 8) * Krows + k0 + tx] = f2bf(T[tx][ty + r * 8]);
  } else {
    const int j = z - 8;
    const int n4 = a.cn4[j];
    const float* X = a.csrc[j];
    u16* Y = a.cdst[j];
    const int blk = blockIdx.y * gridDim.x + blockIdx.x;
    const int stride = gridDim.x * gridDim.y * 256;
    for (int i = blk * 256 + threadIdx.x; i < n4; i += stride) {
      float4 f = ((const float4*)X)[i];
      ushort4 u;
      u.x = f2bf(f.x); u.y = f2bf(f.y); u.z = f2bf(f.z); u.w = f2bf(f.w);
      ((ushort4*)Y)[i] = u;
    }
  }
}

// ---------------------------------------------------------------------------
// Fused QKV projection, wide-wave ring-3 core (round-4/5 proven).
// Grid (48, 13): y<12 vlm (m0=y*256, K=2048), y==12 exp (m0=0, K=1024).
// ---------------------------------------------------------------------------
__global__ __launch_bounds__(256, 2) void g_proj_qkv(
    const u16* __restrict__ Xv, const u16* __restrict__ Xe,
    const u16* __restrict__ Wv_cat, const u16* __restrict__ We_cat,
    u16* __restrict__ Qb, u16* __restrict__ Kb, u16* __restrict__ Vt)
{
  __shared__ __align__(16) u16 As[24576], Bs[12288];   // 72 KiB
  const int y = blockIdx.y;
  const u16* X; const u16* Wt; int Kdim, rows_pb, l_off, m0;
  if (y < 12) { X = Xv; Wt = Wv_cat; Kdim = 2048; rows_pb = 768; l_off = 0; m0 = y * 256; }
  else        { X = Xe; Wt = We_cat; Kdim = 1024; rows_pb = 64;  l_off = 768; m0 = 0; }
  const int t = threadIdx.x;
  const int n0 = blockIdx.x * 128;
  const int r0 = t >> 2;
  const int swk = ((t & 3) ^ ((t >> 3) & 3)) * 8;   // stage-source swizzle
  const u16* aS0 = X + (size_t)(m0 + r0) * Kdim + swk;
  const u16* aS1 = X + (size_t)(m0 + r0 + 64) * Kdim + swk;
  const u16* aS2 = X + (size_t)(m0 + r0 + 128) * Kdim + swk;
  const u16* aS3 = X + (size_t)(m0 + r0 + 192) * Kdim + swk;
  const u16* bS0 = Wt + (size_t)(n0 + r0) * Kdim + swk;
  const u16* bS1 = Wt + (size_t)(n0 + r0 + 64) * Kdim + swk;

  f32x4 acc[8][4] = {};
  gemm_w4(aS0, aS1, aS2, aS3, bS0, bS1, Kdim >> 5, t, As, Bs, acc);

  const int lane = t & 63, fr = lane & 15, q4 = lane >> 4;
  const int w = t >> 6, wm = w >> 1, wn = w & 1;
  const int rbase = m0 + wm * 128 + q4 * 4;
  const int cbase = n0 + wn * 64 + fr;
  const int sect = n0 >> 11;               // block-uniform: 0=Q 1=K 2=V

  if (sect < 2) {
    u16* Out = (sect == 0) ? Qb : Kb;
#pragma unroll
    for (int mt = 0; mt < 8; ++mt) {
#pragma unroll
      for (int rr = 0; rr < 4; ++rr) {
        int m = rbase + mt * 16 + rr;
        int b = m / rows_pb;
        int l = m - b * rows_pb + l_off;
#pragma unroll
        for (int nt = 0; nt < 4; ++nt) {
          int nloc = (cbase + nt * 16) & 2047;
          Out[(((size_t)(b * 8 + (nloc >> 8))) * 832 + l) * 256 + (nloc & 255)] =
              f2bf(acc[mt][nt][rr]);
        }
      }
    }
  } else {
#pragma unroll
    for (int mt = 0; mt < 8; ++mt) {
      int mb = rbase + mt * 16;
      int b = mb / rows_pb;
      int l = mb - b * rows_pb + l_off;     // 4-aligned, no batch crossing
#pragma unroll
      for (int nt = 0; nt < 4; ++nt) {
        int nloc = (cbase + nt * 16) & 2047;
        ushort4 p;
        p.x = f2bf(acc[mt][nt][0]); p.y = f2bf(acc[mt][nt][1]);
        p.z = f2bf(acc[mt][nt][2]); p.w = f2bf(acc[mt][nt][3]);
        *(ushort4*)&Vt[(((size_t)(b * 8 + (nloc >> 8))) * 256 + (nloc & 255)) * 832 + l] = p;
      }
    }
  }
}

// ---------------------------------------------------------------------------
// RoPE in place on bf16 Q,K, vectorized (ushort8 = 16B per access).
// 16 threads/row x 16 rows/block. Q additionally scaled by 1/16.
// ---------------------------------------------------------------------------
__global__ __launch_bounds__(256) void g_rope(
    u16* __restrict__ Q, u16* __restrict__ Kx, const int* __restrict__ pos)
{
  const int t = threadIdx.x;
  const int j = t & 15;                         // d-chunk [j*8, j*8+8)
  const int rowi = blockIdx.x * 16 + (t >> 4);  // (bh,l) flattened
  const int l = rowi % 832;
  const int b = rowi / 6656;                    // 832*8
  const float p = (float)pos[b * 832 + l];
  const size_t base = (size_t)rowi * 256 + j * 8;

  u16x8 q1 = *(const u16x8*)(Q + base);
  u16x8 q2 = *(const u16x8*)(Q + base + 128);
  u16x8 k1 = *(const u16x8*)(Kx + base);
  u16x8 k2 = *(const u16x8*)(Kx + base + 128);
  u16x8 o1, o2, p1, p2;
#pragma unroll
  for (int e = 0; e < 8; ++e) {
    const float inv = exp2f(-(float)(j * 8 + e) * 0.103810252965229910f);
    const float ang = p * inv;
    const float c = cosf(ang), s = sinf(ang);
    float x1 = bf2f(q1[e]), x2 = bf2f(q2[e]);
    o1[e] = f2bf((x1 * c - x2 * s) * 0.0625f);
    o2[e] = f2bf((x2 * c + x1 * s) * 0.0625f);
    x1 = bf2f(k1[e]); x2 = bf2f(k2[e]);
    p1[e] = f2bf(x1 * c - x2 * s);
    p2[e] = f2bf(x2 * c + x1 * s);
  }
  *(u16x8*)(Q + base)        = o1;
  *(u16x8*)(Q + base + 128)  = o2;
  *(u16x8*)(Kx + base)       = p1;
  *(u16x8*)(Kx + base + 128) = p2;
}

// ---------------------------------------------------------------------------
// Single-pass flash attention v3. Grid 416, block 256 (4 waves).
// v2 (static-max softmax, dbuf K/V) + counted split waits:
//   top of kt: issue K[kt+1](4), V[kt+1](4)          (outstanding: V[kt]+8)
//   after QK+softmax:  vmcnt(8)  -> V[kt] landed     (keep kt+1's 8) ; barrier
//   after PV:          vmcnt(4)  -> K[kt+1] landed   (keep V[kt+1])  ; barrier
// Per-wave bookkeeping: each wave issues exactly 4K then 4V per kt, in
// order, so the counted waits retire exactly the intended groups. WAR on
// buf^1: its readers (QK/PV of kt-1) completed before the kt-1 end
// barrier, which precedes kt's stage issue.
// ---------------------------------------------------------------------------
__global__ __launch_bounds__(256) void g_flash(
    const u16* __restrict__ Qb, const u16* __restrict__ Kb,
    const u16* __restrict__ Vt, const float* __restrict__ mask,
    u16* __restrict__ AO)
{
  __shared__ __align__(16) u16 Ks[2][8192];
  __shared__ __align__(16) u16 Vs[2][8192];
  __shared__ __align__(16) u16 Ps[2048];
  const int t = threadIdx.x;
  const int lane = t & 63, w = t >> 6, quad = lane >> 4;
  const int wb = w * 512;

  const int id = blockIdx.x;
  const int x = id & 7, k = id >> 3;
  const int bh = x + 8 * (k / 13);
  const int q0 = (k % 13) * 64;
  const int b = bh >> 3, h = bh & 7;

  const u16* Ksrc = Kb + (size_t)bh * 832 * 256;
  const u16* Vsrc = Vt + (size_t)bh * 256 * 832;
  const float* Mrow = mask + (size_t)b * 832 * 832;

#define STGK(KT, BUF) \
  _Pragma("unroll") \
  for (int p = 0; p < 4; ++p) { \
    int c = p * 256 + t; \
    int row = c >> 5, chk = c & 31; \
    lds16(Ksrc + (size_t)((KT) * 32 + row) * 256 + ((chk ^ (row & 7)) * 8), \
          Ks[BUF] + c * 8); \
  }
#define STGV(KT, BUF) \
  _Pragma("unroll") \
  for (int p = 0; p < 4; ++p) { \
    int c = p * 256 + t; \
    int row = c >> 3; \
    int lc = (c & 7) ^ (row & 7); \
    int dh = 2 * row + (lc >> 2); \
    lds16(Vsrc + (size_t)dh * 832 + (KT) * 32 + (lc & 3) * 8, Vs[BUF] + c * 8); \
  }

  bf16x8 qf[8];
#pragma unroll
  for (int kf = 0; kf < 8; ++kf)
    qf[kf] = *(const bf16x8*)(
        Qb + ((size_t)bh * 832 + q0 + w * 16 + (lane & 15)) * 256 +
        kf * 32 + quad * 8);

  float lsum[4] = {0.f, 0.f, 0.f, 0.f};
  f32x4 oa[16] = {};

  STGK(0, 0); STGV(0, 0);
  asm volatile("s_waitcnt vmcnt(0)" ::: "memory");
  __builtin_amdgcn_s_barrier();

  for (int kt = 0; kt < 26; ++kt) {
    const int buf = kt & 1;
    const bool more = (kt + 1 < 26);
    if (more) { STGK(kt + 1, buf ^ 1); STGV(kt + 1, buf ^ 1); }

    float mv[4][2];
#pragma unroll
    for (int r = 0; r < 4; ++r) {
      int q = q0 + w * 16 + quad * 4 + r;
      const float* mrp = Mrow + (size_t)q * 832 + kt * 32 + (lane & 15);
      mv[r][0] = mrp[0];
      mv[r][1] = mrp[16];
    }

    f32x4 sa[2] = {};
#pragma unroll
    for (int ks = 0; ks < 8; ++ks)
#pragma unroll
      for (int nt = 0; nt < 2; ++nt) {
        int krow = nt * 16 + (lane & 15);
        bf16x8 kb = *(const bf16x8*)(
            Ks[buf] + krow * 256 + (((ks * 4 + quad) ^ (krow & 7)) * 8));
        sa[nt] = MM(qf[ks], kb, sa[nt]);
      }

#pragma unroll
    for (int r = 0; r < 4; ++r) {
      int prow = quad * 4 + r;
      float p0 = __expf(sa[0][r] + mv[r][0]);
      float p1 = __expf(sa[1][r] + mv[r][1]);
      lsum[r] += p0 + p1;
      int s0 = ((lane >> 3) & 1) ^ quad;
      int s1 = (2 | ((lane >> 3) & 1)) ^ quad;
      Ps[wb + prow * 32 + s0 * 8 + (lane & 7)] = f2bf(p0);
      Ps[wb + prow * 32 + s1 * 8 + (lane & 7)] = f2bf(p1);
    }

    // V[kt] guaranteed in LDS across all waves before PV
    if (more) asm volatile("s_waitcnt vmcnt(8)" ::: "memory");
    else      asm volatile("s_waitcnt vmcnt(0)" ::: "memory");
    __builtin_amdgcn_s_barrier();

    int prow2 = lane & 15;
    bf16x8 pa = *(const bf16x8*)(
        Ps + wb + prow2 * 32 + ((quad ^ ((prow2 >> 2) & 3)) * 8));
#pragma unroll
    for (int nt = 0; nt < 16; ++nt) {
      int dh = nt * 16 + (lane & 15);
      int row = dh >> 1;
      int lc = ((dh & 1) << 2) | quad;
      bf16x8 vb = *(const bf16x8*)(Vs[buf] + row * 64 + ((lc ^ (row & 7)) * 8));
      oa[nt] = MM(pa, vb, oa[nt]);
    }

    if (more) {
      asm volatile("s_waitcnt vmcnt(4)" ::: "memory");  // K[kt+1] landed
      __builtin_amdgcn_s_barrier();
    }
  }

  float linv[4];
#pragma unroll
  for (int r = 0; r < 4; ++r) {
    float s = lsum[r];
    s += __shfl_xor(s, 1);
    s += __shfl_xor(s, 2);
    s += __shfl_xor(s, 4);
    s += __shfl_xor(s, 8);
    linv[r] = 1.0f / s;
  }
#pragma unroll
  for (int r = 0; r < 4; ++r) {
    size_t l = q0 + w * 16 + quad * 4 + r;
    u16* dst = AO + ((size_t)b * 832 + l) * 2048 + h * 256 + (lane & 15);
#pragma unroll
    for (int nt = 0; nt < 16; ++nt)
      dst[nt * 16] = f2bf(oa[nt][r] * linv[r]);
  }
#undef STGK
#undef STGV
}

// ---------------------------------------------------------------------------
// Fused output projection, wide-wave ring-3 core. Grid (16, 13):
// y<12 vlm (N=2048), y==12 exp (x<8, N=1024). K=2048 both. Block 256 thr.
// ---------------------------------------------------------------------------
__global__ __launch_bounds__(256, 2) void g_oproj2(
    const u16* __restrict__ AO, const u16* __restrict__ Wov,
    const u16* __restrict__ Woe, float* __restrict__ out)
{
  __shared__ __align__(16) u16 As[24576], Bs[12288];   // 72 KiB
  const int y = blockIdx.y;
  const u16* Wt; float* C; int N, rows_pb, l_off, m0;
  if (y < 12) { Wt = Wov; C = out; N = 2048; rows_pb = 768; l_off = 0; m0 = y * 256; }
  else {
    if (blockIdx.x >= 8) return;
    Wt = Woe; C = out + (size_t)4 * 768 * 2048; N = 1024; rows_pb = 64; l_off = 768; m0 = 0;
  }
  const int t = threadIdx.x;
  const int n0 = blockIdx.x * 128;
  const int r0 = t >> 2;
  const int swk = ((t & 3) ^ ((t >> 3) & 3)) * 8;
  const u16* aSp[4];
#pragma unroll
  for (int i = 0; i < 4; ++i) {
    int mr = m0 + i * 64 + r0;
    int ba = mr / rows_pb;
    aSp[i] = AO + ((size_t)ba * 832 + (mr - ba * rows_pb) + l_off) * 2048 + swk;
  }
  const u16* bS0 = Wt + (size_t)(n0 + r0) * 2048 + swk;
  const u16* bS1 = Wt + (size_t)(n0 + r0 + 64) * 2048 + swk;

  f32x4 acc[8][4] = {};
  gemm_w4(aSp[0], aSp[1], aSp[2], aSp[3], bS0, bS1, 64, t, As, Bs, acc);

  const int lane = t & 63, fr = lane & 15, q4 = lane >> 4;
  const int w = t >> 6, wm = w >> 1, wn = w & 1;
  const int rbase = m0 + wm * 128 + q4 * 4;
  const int cbase = n0 + wn * 64 + fr;
#pragma unroll
  for (int mt = 0; mt < 8; ++mt)
#pragma unroll
    for (int rr = 0; rr < 4; ++rr) {
      size_t m = rbase + mt * 16 + rr;
#pragma unroll
      for (int nt = 0; nt < 4; ++nt)
        C[m * N + cbase + nt * 16] = acc[mt][nt][rr];
    }
}

// ---------------------------------------------------------------------------
extern "C" void kernel_launch(void* const* d_in, const int* in_sizes, int n_in,
                              void* d_out, int out_size, void* d_ws, size_t ws_size,
                              hipStream_t stream)
{
  const float* vlm_h = (const float*)d_in[0];
  const float* exp_h = (const float*)d_in[1];
  const float* mask  = (const float*)d_in[2];
  const int*   pos   = (const int*)d_in[3];
  const float* wq_v  = (const float*)d_in[4];
  const float* wk_v  = (const float*)d_in[5];
  const float* wv_v  = (const float*)d_in[6];
  const float* wo_v  = (const float*)d_in[7];
  const float* wq_e  = (const float*)d_in[8];
  const float* wk_e  = (const float*)d_in[9];
  const float* wv_e  = (const float*)d_in[10];
  const float* wo_e  = (const float*)d_in[11];
  float* out = (float*)d_out;

  // ---- workspace layout (~118 MB) ----
  u16* U = (u16*)d_ws;
  u16* Xv   = U; U += (size_t)4 * 768 * 2048;
  u16* Xe   = U; U += (size_t)4 * 64 * 1024;
  u16* Wcv  = U; U += (size_t)6144 * 2048;   // [Wq_v^T | Wk_v^T | Wv_v^T]
  u16* Wce  = U; U += (size_t)6144 * 1024;   // [Wq_e^T | Wk_e^T | Wv_e^T]
  u16* Wov  = U; U += (size_t)2048 * 2048;
  u16* Woe  = U; U += (size_t)1024 * 2048;
  u16* Qb   = U; U += (size_t)32 * 832 * 256;
  u16* Kb   = U; U += (size_t)32 * 832 * 256;
  u16* Vt   = U; U += (size_t)32 * 256 * 832;
  u16* AO   = U; U += (size_t)4 * 832 * 2048;

  const dim3 blk(256);

  PrepArgs pa;
  pa.tsrc[0] = wq_v; pa.tdst[0] = Wcv;                        pa.tK[0] = 2048; pa.tN[0] = 2048;
  pa.tsrc[1] = wk_v; pa.tdst[1] = Wcv + (size_t)2048 * 2048;  pa.tK[1] = 2048; pa.tN[1] = 2048;
  pa.tsrc[2] = wv_v; pa.tdst[2] = Wcv + (size_t)4096 * 2048;  pa.tK[2] = 2048; pa.tN[2] = 2048;
  pa.tsrc[3] = wo_v; pa.tdst[3] = Wov;                        pa.tK[3] = 2048; pa.tN[3] = 2048;
  pa.tsrc[4] = wq_e; pa.tdst[4] = Wce;                        pa.tK[4] = 1024; pa.tN[4] = 2048;
  pa.tsrc[5] = wk_e; pa.tdst[5] = Wce + (size_t)2048 * 1024;  pa.tK[5] = 1024; pa.tN[5] = 2048;
  pa.tsrc[6] = wv_e; pa.tdst[6] = Wce + (size_t)4096 * 1024;  pa.tK[6] = 1024; pa.tN[6] = 2048;
  pa.tsrc[7] = wo_e; pa.tdst[7] = Woe;                        pa.tK[7] = 2048; pa.tN[7] = 1024;
  pa.csrc[0] = vlm_h; pa.cdst[0] = Xv; pa.cn4[0] = 1572864;
  pa.csrc[1] = exp_h; pa.cdst[1] = Xe; pa.cn4[1] = 65536;
  g_prep<<<dim3(64, 64, 10), blk, 0, stream>>>(pa);

  // fused QKV projection, wide-wave ring-3 core (round-5 proven)
  g_proj_qkv<<<dim3(48, 13, 1), blk, 0, stream>>>(Xv, Xe, Wcv, Wce, Qb, Kb, Vt);

  // vectorized RoPE
  g_rope<<<dim3(1664), blk, 0, stream>>>(Qb, Kb, pos);

  // flash attention v3 (counted split waits)
  g_flash<<<dim3(416), blk, 0, stream>>>(Qb, Kb, Vt, mask, AO);

  g_oproj2<<<dim3(16, 13, 1), blk, 0, stream>>>(AO, Wov, Woe, out);
}